// Round 9
// baseline (144.711 us; speedup 1.0000x reference)
//
#include <hip/hip_runtime.h>
#include <hip/hip_bf16.h>
#include <cstdint>
#include <cstddef>

#define HDIM 512
#define NEXP 8
#define BM 128
#define BN 128
#define BK 32

typedef __bf16 bf16t;
typedef __attribute__((ext_vector_type(8))) __bf16 bf16x8;
typedef __attribute__((ext_vector_type(4))) float f32x4;

__device__ inline void gload_lds16(const void* g, void* l) {
  __builtin_amdgcn_global_load_lds(
      (const __attribute__((address_space(1))) void*)g,
      (__attribute__((address_space(3))) void*)l, 16, 0, 0);
}

// ---------------- zero output (fallback path only) ----------------
__global__ void k_zero(float4* __restrict__ p, int n4) {
  int i = blockIdx.x * blockDim.x + threadIdx.x;
  int st = gridDim.x * blockDim.x;
  for (; i < n4; i += st) p[i] = make_float4(0.f, 0.f, 0.f, 0.f);
}

// -------- W[e][h][o] f32 -> wT[e][o][h] bf16 (transpose+convert) + init ----
__global__ void k_wt(const float* __restrict__ W, bf16t* __restrict__ wT,
                     int* __restrict__ cursor) {
  if (blockIdx.x == 0 && threadIdx.x < NEXP) cursor[threadIdx.x] = 0;
  __shared__ float t[64][65];
  int b = blockIdx.x;
  int e = b >> 6, ht = (b >> 3) & 7, ot = b & 7;
  const float* We = W + (size_t)e * HDIM * HDIM;
  int tid = threadIdx.x;
  int c = tid & 63, rr = tid >> 6;
#pragma unroll
  for (int i = 0; i < 16; ++i) {
    int h = i * 4 + rr;
    t[h][c] = We[(size_t)(ht * 64 + h) * HDIM + ot * 64 + c];
  }
  __syncthreads();
  bf16t* dst = wT + (size_t)e * HDIM * HDIM;
#pragma unroll
  for (int i = 0; i < 16; ++i) {
    int o = i * 4 + rr;
    dst[(size_t)(ot * 64 + o) * HDIM + ht * 64 + c] = (bf16t)t[c][o];
  }
}

__device__ inline float dot8(float4 x0, float4 x1, float4 wa, float4 wb) {
  return x0.x * wa.x + x0.y * wa.y + x0.z * wa.z + x0.w * wa.w +
         x1.x * wb.x + x1.y * wb.y + x1.z * wb.z + x1.w * wb.w;
}

// ---- router+scatter: wave/token, all-scalar; btok entry = n | (slot<<30) ---
#define ROUTE_TOKEN(nn, xv0, xv1, slot)                                        \
  if ((nn) < ntok) {                                                           \
    float s0 = dot8(xv0, xv1, r0a, r0b), s1 = dot8(xv0, xv1, r1a, r1b);        \
    float s2 = dot8(xv0, xv1, r2a, r2b), s3 = dot8(xv0, xv1, r3a, r3b);        \
    float s4 = dot8(xv0, xv1, r4a, r4b), s5 = dot8(xv0, xv1, r5a, r5b);        \
    float s6 = dot8(xv0, xv1, r6a, r6b), s7 = dot8(xv0, xv1, r7a, r7b);        \
    float p0 = __shfl_xor(s0, 1), p1 = __shfl_xor(s1, 1);                      \
    float p2 = __shfl_xor(s2, 1), p3 = __shfl_xor(s3, 1);                      \
    float p4 = __shfl_xor(s4, 1), p5 = __shfl_xor(s5, 1);                      \
    float p6 = __shfl_xor(s6, 1), p7 = __shfl_xor(s7, 1);                      \
    float t0 = c0 ? s4 + p4 : s0 + p0;                                         \
    float t1 = c0 ? s5 + p5 : s1 + p1;                                         \
    float t2 = c0 ? s6 + p6 : s2 + p2;                                         \
    float t3 = c0 ? s7 + p7 : s3 + p3;                                         \
    float q0 = __shfl_xor(t0, 2), q1 = __shfl_xor(t1, 2);                      \
    float q2 = __shfl_xor(t2, 2), q3 = __shfl_xor(t3, 2);                      \
    float u0 = c1 ? t2 + q2 : t0 + q0;                                         \
    float u1 = c1 ? t3 + q3 : t1 + q1;                                         \
    float z0 = __shfl_xor(u0, 4), z1 = __shfl_xor(u1, 4);                      \
    float wvv = c2 ? u1 + z1 : u0 + z0;                                        \
    wvv += __shfl_xor(wvv, 8);                                                 \
    wvv += __shfl_xor(wvv, 16);                                                \
    wvv += __shfl_xor(wvv, 32);                                                \
    float lg0 = __shfl(wvv, 0), lg1 = __shfl(wvv, 4);                          \
    float lg2 = __shfl(wvv, 2), lg3 = __shfl(wvv, 6);                          \
    float lg4 = __shfl(wvv, 1), lg5 = __shfl(wvv, 5);                          \
    float lg6 = __shfl(wvv, 3), lg7 = __shfl(wvv, 7);                          \
    float mm = fmaxf(fmaxf(fmaxf(lg0, lg1), fmaxf(lg2, lg3)),                  \
                     fmaxf(fmaxf(lg4, lg5), fmaxf(lg6, lg7)));                 \
    float e0 = expf(lg0 - mm), e1 = expf(lg1 - mm);                            \
    float e2 = expf(lg2 - mm), e3 = expf(lg3 - mm);                            \
    float e4 = expf(lg4 - mm), e5 = expf(lg5 - mm);                            \
    float e6 = expf(lg6 - mm), e7 = expf(lg7 - mm);                            \
    float SS = e0 + e1 + e2 + e3 + e4 + e5 + e6 + e7;                          \
    float inv = 1.f / SS;                                                      \
    e0 *= inv; e1 *= inv; e2 *= inv; e3 *= inv;                                \
    e4 *= inv; e5 *= inv; e6 *= inv; e7 *= inv;                                \
    int b0 = 0; float v0 = e0;                                                 \
    if (e1 > v0) { b0 = 1; v0 = e1; }                                          \
    if (e2 > v0) { b0 = 2; v0 = e2; }                                          \
    if (e3 > v0) { b0 = 3; v0 = e3; }                                          \
    if (e4 > v0) { b0 = 4; v0 = e4; }                                          \
    if (e5 > v0) { b0 = 5; v0 = e5; }                                          \
    if (e6 > v0) { b0 = 6; v0 = e6; }                                          \
    if (e7 > v0) { b0 = 7; v0 = e7; }                                          \
    int b1 = -1; float v1 = -1.f;                                              \
    if (b0 != 0) { b1 = 0; v1 = e0; }                                          \
    if (b0 != 1 && e1 > v1) { b1 = 1; v1 = e1; }                               \
    if (b0 != 2 && e2 > v1) { b1 = 2; v1 = e2; }                               \
    if (b0 != 3 && e3 > v1) { b1 = 3; v1 = e3; }                               \
    if (b0 != 4 && e4 > v1) { b1 = 4; v1 = e4; }                               \
    if (b0 != 5 && e5 > v1) { b1 = 5; v1 = e5; }                               \
    if (b0 != 6 && e6 > v1) { b1 = 6; v1 = e6; }                               \
    if (b0 != 7 && e7 > v1) { b1 = 7; v1 = e7; }                               \
    float ssum = v0 + v1 + 1e-6f;                                              \
    if (lane == 0) {                                                           \
      sb0[slot] = b0; sb1[slot] = b1;                                          \
      sv0[slot] = v0 / ssum; sv1[slot] = v1 / ssum;                            \
      sp0[slot] = atomicAdd(&lcnt[b0], 1);                                     \
      sp1[slot] = atomicAdd(&lcnt[b1], 1);                                     \
    }                                                                          \
    bf16x8 hh;                                                                 \
    hh[0] = (bf16t)xv0.x; hh[1] = (bf16t)xv0.y;                                \
    hh[2] = (bf16t)xv0.z; hh[3] = (bf16t)xv0.w;                                \
    hh[4] = (bf16t)xv1.x; hh[5] = (bf16t)xv1.y;                                \
    hh[6] = (bf16t)xv1.z; hh[7] = (bf16t)xv1.w;                                \
    *(bf16x8*)(xb + (size_t)(nn)*HDIM + lane * 8) = hh;                        \
  }

__global__ __launch_bounds__(256, 2) void k_router(
    const float* __restrict__ x, const float* __restrict__ rw,
    int* __restrict__ cursor, bf16t* __restrict__ xb, int* __restrict__ btok,
    float* __restrict__ bw, int ntok) {
  __shared__ int lcnt[NEXP], gb[NEXP];
  __shared__ int sb0[16], sb1[16], sp0[16], sp1[16];
  __shared__ float sv0[16], sv1[16];
  int tid = threadIdx.x;
  if (tid < NEXP) lcnt[tid] = 0;
  __syncthreads();
  int lane = tid & 63;
  int c0 = lane & 1, c1 = (lane >> 1) & 1, c2 = (lane >> 2) & 1;
  int l2 = lane * 2;
  const float4* rwp = (const float4*)rw;
  float4 r0a = rwp[0 * 128 + l2], r0b = rwp[0 * 128 + l2 + 1];
  float4 r1a = rwp[1 * 128 + l2], r1b = rwp[1 * 128 + l2 + 1];
  float4 r2a = rwp[2 * 128 + l2], r2b = rwp[2 * 128 + l2 + 1];
  float4 r3a = rwp[3 * 128 + l2], r3b = rwp[3 * 128 + l2 + 1];
  float4 r4a = rwp[4 * 128 + l2], r4b = rwp[4 * 128 + l2 + 1];
  float4 r5a = rwp[5 * 128 + l2], r5b = rwp[5 * 128 + l2 + 1];
  float4 r6a = rwp[6 * 128 + l2], r6b = rwp[6 * 128 + l2 + 1];
  float4 r7a = rwp[7 * 128 + l2], r7b = rwp[7 * 128 + l2 + 1];
  int wv = tid >> 6;
  int nb = (blockIdx.x * 4 + wv) * 4;
  const float4* xp = (const float4*)x;
  int lastn = ntok - 1;
  int i0 = nb + 0 > lastn ? lastn : nb + 0;
  int i1 = nb + 1 > lastn ? lastn : nb + 1;
  int i2 = nb + 2 > lastn ? lastn : nb + 2;
  int i3 = nb + 3 > lastn ? lastn : nb + 3;
  float4 x0a = xp[(size_t)i0 * 128 + l2], x0b = xp[(size_t)i0 * 128 + l2 + 1];
  float4 x1a = xp[(size_t)i1 * 128 + l2], x1b = xp[(size_t)i1 * 128 + l2 + 1];
  float4 x2a = xp[(size_t)i2 * 128 + l2], x2b = xp[(size_t)i2 * 128 + l2 + 1];
  float4 x3a = xp[(size_t)i3 * 128 + l2], x3b = xp[(size_t)i3 * 128 + l2 + 1];
  ROUTE_TOKEN(nb + 0, x0a, x0b, wv * 4 + 0)
  ROUTE_TOKEN(nb + 1, x1a, x1b, wv * 4 + 1)
  ROUTE_TOKEN(nb + 2, x2a, x2b, wv * 4 + 2)
  ROUTE_TOKEN(nb + 3, x3a, x3b, wv * 4 + 3)
  __syncthreads();
  if (tid < NEXP) gb[tid] = lcnt[tid] ? atomicAdd(&cursor[tid], lcnt[tid]) : 0;
  __syncthreads();
  if (tid < 16) {
    int n = blockIdx.x * 16 + tid;
    if (n < ntok) {
      int b0 = sb0[tid], r0 = gb[b0] + sp0[tid];
      btok[b0 * ntok + r0] = n;              // slot 0
      bw[b0 * ntok + r0] = sv0[tid];
      int b1 = sb1[tid], r1 = gb[b1] + sp1[tid];
      btok[b1 * ntok + r1] = n | (1 << 30);  // slot 1
      bw[b1 * ntok + r1] = sv1[tid];
    }
  }
}

// ------- offsets + exact tile list (128-row tiles), lane-parallel ----------
__global__ void k_offsets(const int* __restrict__ counts, int* __restrict__ offs,
                          int* __restrict__ ntiles, int* __restrict__ tlist) {
  int lane = threadIdx.x;
  if (lane < NEXP) {
    int s = 0, tstart = 0;
    for (int i = 0; i < lane; ++i) {
      s += counts[i];
      tstart += (counts[i] + BM - 1) / BM;
    }
    offs[lane] = s;
    int rtn = (counts[lane] + BM - 1) / BM;
    for (int r = 0; r < rtn; ++r) tlist[tstart + r] = (lane << 16) | r;
    if (lane == NEXP - 1) ntiles[0] = tstart + rtn;
  }
}

// -------- grouped GEMM: 128x128, BK=32, 4 waves, 2 bufs, 4 blocks/CU --------
// Swizzle (CORRECTED): at 64B row pitch the bank set depends on row>>1, so
// LDS[row][c] holds global chunk c ^ ((row>>1)&3); staging source pre-swizzled
// (linear gload_lds dest), read applies same XOR -> conflict-free 8-lane groups.
// VAR: 0 = production; 1 = ablation, A-addresses sequential (no gather);
//      2 = ablation, stage first 2 steps only (no steady-state VMEM).
template <int VAR, bool EO>
__global__ __launch_bounds__(256, 4) void k_gemm(
    const bf16t* __restrict__ xb, const bf16t* __restrict__ wT,
    const int* __restrict__ btok, const float* __restrict__ bw,
    const int* __restrict__ counts, const int* __restrict__ ntiles,
    const int* __restrict__ tlist, bf16t* __restrict__ eout2,
    float* __restrict__ out, int ntok) {
  __shared__ bf16t Asm[2][BM * BK];  // 2 x 8KB
  __shared__ bf16t Bsm[2][BN * BK];  // 2 x 8KB
  int bid = blockIdx.x;
  int t = bid >> 2, ct = bid & 3;
  if (t >= ntiles[0]) return;
  int pk = tlist[t];
  int e = pk >> 16, rt = pk & 0xffff;
  int cnt = counts[e];
  int m0 = rt * BM, n0 = ct * BN;
  int tid = threadIdx.x;
  int lane = tid & 63;
  int wv = tid >> 6, wr = wv >> 1, wc = wv & 1;  // 2x2 wave grid

  // staging ids; source chunk pre-swizzled with (row>>1)&3
  int id0 = wv * 128 + lane;
  int id1 = wv * 128 + 64 + lane;
  int row0 = id0 >> 2, cc0 = (id0 & 3) ^ ((row0 >> 1) & 3);
  int row1 = id1 >> 2, cc1 = (id1 & 3) ^ ((row1 >> 1) & 3);
  const bf16t* bsrc0 = wT + (size_t)(e * HDIM + n0 + row0) * HDIM + cc0 * 8;
  const bf16t* bsrc1 = wT + (size_t)(e * HDIM + n0 + row1) * HDIM + cc1 * 8;
  int gr0 = m0 + row0; if (gr0 > cnt - 1) gr0 = cnt - 1;
  int gr1 = m0 + row1; if (gr1 > cnt - 1) gr1 = cnt - 1;
  int tok0, tok1;
  if (VAR == 1) {  // ablation: sequential A rows (gather randomness removed)
    tok0 = gr0; tok1 = gr1;
  } else {
    tok0 = btok[e * ntok + gr0] & 0xFFFFF;
    tok1 = btok[e * ntok + gr1] & 0xFFFFF;
  }
  const bf16t* asrc0 = xb + (size_t)tok0 * HDIM + cc0 * 8;
  const bf16t* asrc1 = xb + (size_t)tok1 * HDIM + cc1 * 8;
  int d0 = id0 * 8, d1 = id1 * 8;  // linear LDS dest (lane stride 16B)

  auto STAGE = [&](int b, int kt) {
    int k0 = kt * BK;
    gload_lds16(bsrc0 + k0, &Bsm[b][d0]);
    gload_lds16(bsrc1 + k0, &Bsm[b][d1]);
    gload_lds16(asrc0 + k0, &Asm[b][d0]);
    gload_lds16(asrc1 + k0, &Asm[b][d1]);
  };

  f32x4 acc[4][4];
#pragma unroll
  for (int a = 0; a < 4; ++a)
#pragma unroll
    for (int b = 0; b < 4; ++b) acc[a][b] = f32x4{0.f, 0.f, 0.f, 0.f};

  // read-side: global chunk g=lane>>4 at row r lives at lds chunk g^((r>>1)&3)
  int swk = ((lane >> 4) ^ ((lane >> 1) & 3)) * 8;
  int abase = (wr * 64 + (lane & 15)) * BK + swk;
  int bbase = (wc * 64 + (lane & 15)) * BK + swk;

  constexpr int NT = HDIM / BK;  // 16
  STAGE(0, 0);
#pragma unroll
  for (int kt = 0; kt < NT; ++kt) {
    int cur = kt & 1;
    bool doStage = (VAR == 2) ? (kt + 1 < 2) : (kt + 1 < NT);
    if (doStage) {
      STAGE(cur ^ 1, kt + 1);
      asm volatile("s_waitcnt vmcnt(4)" ::: "memory");  // stage kt landed
    } else {
      asm volatile("s_waitcnt vmcnt(0)" ::: "memory");
    }
    __builtin_amdgcn_s_barrier();
    __builtin_amdgcn_sched_barrier(0);
    bf16x8 af[4], bfr[4];
#pragma unroll
    for (int mi = 0; mi < 4; ++mi)
      af[mi] = *(const bf16x8*)(&Asm[cur][abase + mi * 16 * BK]);
#pragma unroll
    for (int ni = 0; ni < 4; ++ni)
      bfr[ni] = *(const bf16x8*)(&Bsm[cur][bbase + ni * 16 * BK]);
#pragma unroll
    for (int mi = 0; mi < 4; ++mi)
#pragma unroll
      for (int ni = 0; ni < 4; ++ni)
        acc[mi][ni] =
            __builtin_amdgcn_mfma_f32_16x16x32_bf16(af[mi], bfr[ni], acc[mi][ni], 0, 0, 0);
    __builtin_amdgcn_s_barrier();  // frag reads done before buf reuse
    __builtin_amdgcn_sched_barrier(0);
  }

  // Epilogue: D[row][col]: col = lane&15, row = (lane>>4)*4 + j  [m89/m91]
  int col0 = n0 + wc * 64 + (lane & 15);
  int rb = wr * 64 + ((lane >> 4) << 2);
#pragma unroll
  for (int mi = 0; mi < 4; ++mi) {
#pragma unroll
    for (int j = 0; j < 4; ++j) {
      int rrow = m0 + rb + mi * 16 + j;
      if (rrow < cnt) {
        int entry = btok[e * ntok + rrow];
        int tok = entry & 0xFFFFF;
        int slot = (entry >> 30) & 1;
        float w = bw[e * ntok + rrow];
        if (EO) {
          bf16t* orow = eout2 + ((size_t)tok * 2 + slot) * HDIM + col0;
          orow[0] = (bf16t)(w * acc[mi][0][j]);
          orow[16] = (bf16t)(w * acc[mi][1][j]);
          orow[32] = (bf16t)(w * acc[mi][2][j]);
          orow[48] = (bf16t)(w * acc[mi][3][j]);
        } else {
          float* orow = out + (size_t)tok * HDIM + col0;
#pragma unroll
          for (int ni = 0; ni < 4; ++ni)
            atomicAdd(orow + ni * 16, w * acc[mi][ni][j]);
        }
      }
    }
  }
}

// -------- combine: out[n] = eout2[2n] + eout2[2n+1]  (pure stream) ----------
__global__ void k_combine(const bf16t* __restrict__ eout2, float* __restrict__ out,
                          int ntok) {
  int lane = threadIdx.x & 63;
  int gw = (blockIdx.x * blockDim.x + threadIdx.x) >> 6;
  int nw = (gridDim.x * blockDim.x) >> 6;
  for (int n = gw; n < ntok; n += nw) {
    bf16x8 a = *(const bf16x8*)(eout2 + (size_t)(2 * n) * HDIM + lane * 8);
    bf16x8 b = *(const bf16x8*)(eout2 + (size_t)(2 * n + 1) * HDIM + lane * 8);
    float4 o0, o1;
    o0.x = (float)a[0] + (float)b[0];
    o0.y = (float)a[1] + (float)b[1];
    o0.z = (float)a[2] + (float)b[2];
    o0.w = (float)a[3] + (float)b[3];
    o1.x = (float)a[4] + (float)b[4];
    o1.y = (float)a[5] + (float)b[5];
    o1.z = (float)a[6] + (float)b[6];
    o1.w = (float)a[7] + (float)b[7];
    float4* dst = (float4*)(out + (size_t)n * HDIM + lane * 8);
    dst[0] = o0; dst[1] = o1;
  }
}

extern "C" void kernel_launch(void* const* d_in, const int* in_sizes, int n_in,
                              void* d_out, int out_size, void* d_ws, size_t ws_size,
                              hipStream_t stream) {
  const float* x = (const float*)d_in[0];
  const float* rw = (const float*)d_in[1];
  const float* W = (const float*)d_in[2];
  float* out = (float*)d_out;
  int ntok = in_sizes[0] / HDIM;  // 16384 for B=4,S=4096
  if (ntok <= 0) return;
  int maxT = ((2 * ntok + BM - 1) / BM) + NEXP - 1;

  // workspace layout
  char* ws = (char*)d_ws;
  size_t o = 0;
  bf16t* wT = (bf16t*)(ws + o); o += (size_t)NEXP * HDIM * HDIM * sizeof(bf16t);
  int* meta = (int*)(ws + o); o += 256;  // cursor/counts[8], offs[8], ntiles
  int* cursor = meta;                    // doubles as counts after router
  int* offs = meta + 8;
  int* ntiles = meta + 16;
  int* tlist = (int*)(ws + o); o += (size_t)((maxT * 4 + 255) & ~255);
  int* btok = (int*)(ws + o); o += (size_t)NEXP * ntok * 4;   // [e][ntok]
  float* bw = (float*)(ws + o); o += (size_t)NEXP * ntok * 4;
  bf16t* xb = (bf16t*)(ws + o); o += (size_t)ntok * HDIM * sizeof(bf16t);
  size_t oBase = o;
  bf16t* eout2 = (bf16t*)(ws + o); o += (size_t)2 * ntok * HDIM * sizeof(bf16t);
  if (ws_size < oBase) return;           // ~23 MB minimum
  int useEO = (ws_size >= o) ? 1 : 0;    // +33.6 MB no-atomic path

  k_wt<<<dim3(512), dim3(256), 0, stream>>>(W, wT, cursor);
  k_router<<<dim3((ntok + 15) / 16), dim3(256), 0, stream>>>(x, rw, cursor, xb, btok, bw,
                                                             ntok);
  k_offsets<<<dim3(1), dim3(64), 0, stream>>>(cursor, offs, ntiles, tlist);
  if (useEO) {
    k_gemm<0, true><<<dim3(maxT * 4), dim3(256), 0, stream>>>(
        xb, wT, btok, bw, cursor, ntiles, tlist, eout2, out, ntok);
    k_combine<<<dim3(2048), dim3(256), 0, stream>>>(eout2, out, ntok);
    // ---- ablation dispatches (write only the now-dead eout2; out is final) --
    k_gemm<1, true><<<dim3(maxT * 4), dim3(256), 0, stream>>>(
        xb, wT, btok, bw, cursor, ntiles, tlist, eout2, out, ntok);
    k_gemm<2, true><<<dim3(maxT * 4), dim3(256), 0, stream>>>(
        xb, wT, btok, bw, cursor, ntiles, tlist, eout2, out, ntok);
  } else {
    k_zero<<<dim3(2048), dim3(256), 0, stream>>>((float4*)out, ntok * HDIM / 4);
    k_gemm<0, false><<<dim3(maxT * 4), dim3(256), 0, stream>>>(
        xb, wT, btok, bw, cursor, ntiles, tlist, eout2, out, ntok);
  }
}

// Round 10
// 77.653 us; speedup vs baseline: 1.8636x; 1.8636x over previous
//
#include <hip/hip_runtime.h>
#include <hip/hip_bf16.h>
#include <cstdint>
#include <cstddef>

#define HDIM 512
#define NEXP 8
#define BM 128
#define BN 128
#define BK 32

typedef __bf16 bf16t;
typedef __attribute__((ext_vector_type(8))) __bf16 bf16x8;
typedef __attribute__((ext_vector_type(4))) float f32x4;

__device__ inline void gload_lds16(const void* g, void* l) {
  __builtin_amdgcn_global_load_lds(
      (const __attribute__((address_space(1))) void*)g,
      (__attribute__((address_space(3))) void*)l, 16, 0, 0);
}

// ---------------- zero output (fallback path only) ----------------
__global__ void k_zero(float4* __restrict__ p, int n4) {
  int i = blockIdx.x * blockDim.x + threadIdx.x;
  int st = gridDim.x * blockDim.x;
  for (; i < n4; i += st) p[i] = make_float4(0.f, 0.f, 0.f, 0.f);
}

// -------- W[e][h][o] f32 -> wT[e][o][h] bf16 (transpose+convert) + init ----
__global__ void k_wt(const float* __restrict__ W, bf16t* __restrict__ wT,
                     int* __restrict__ cursor) {
  if (blockIdx.x == 0 && threadIdx.x < NEXP) cursor[threadIdx.x] = 0;
  __shared__ float t[64][65];
  int b = blockIdx.x;
  int e = b >> 6, ht = (b >> 3) & 7, ot = b & 7;
  const float* We = W + (size_t)e * HDIM * HDIM;
  int tid = threadIdx.x;
  int c = tid & 63, rr = tid >> 6;
#pragma unroll
  for (int i = 0; i < 16; ++i) {
    int h = i * 4 + rr;
    t[h][c] = We[(size_t)(ht * 64 + h) * HDIM + ot * 64 + c];
  }
  __syncthreads();
  bf16t* dst = wT + (size_t)e * HDIM * HDIM;
#pragma unroll
  for (int i = 0; i < 16; ++i) {
    int o = i * 4 + rr;
    dst[(size_t)(ot * 64 + o) * HDIM + ht * 64 + c] = (bf16t)t[c][o];
  }
}

__device__ inline float dot8(float4 x0, float4 x1, float4 wa, float4 wb) {
  return x0.x * wa.x + x0.y * wa.y + x0.z * wa.z + x0.w * wa.w +
         x1.x * wb.x + x1.y * wb.y + x1.z * wb.z + x1.w * wb.w;
}

// ---- router+scatter: wave/token, all-scalar; btok entry = n | (slot<<30) ---
#define ROUTE_TOKEN(nn, xv0, xv1, slot)                                        \
  if ((nn) < ntok) {                                                           \
    float s0 = dot8(xv0, xv1, r0a, r0b), s1 = dot8(xv0, xv1, r1a, r1b);        \
    float s2 = dot8(xv0, xv1, r2a, r2b), s3 = dot8(xv0, xv1, r3a, r3b);        \
    float s4 = dot8(xv0, xv1, r4a, r4b), s5 = dot8(xv0, xv1, r5a, r5b);        \
    float s6 = dot8(xv0, xv1, r6a, r6b), s7 = dot8(xv0, xv1, r7a, r7b);        \
    float p0 = __shfl_xor(s0, 1), p1 = __shfl_xor(s1, 1);                      \
    float p2 = __shfl_xor(s2, 1), p3 = __shfl_xor(s3, 1);                      \
    float p4 = __shfl_xor(s4, 1), p5 = __shfl_xor(s5, 1);                      \
    float p6 = __shfl_xor(s6, 1), p7 = __shfl_xor(s7, 1);                      \
    float t0 = c0 ? s4 + p4 : s0 + p0;                                         \
    float t1 = c0 ? s5 + p5 : s1 + p1;                                         \
    float t2 = c0 ? s6 + p6 : s2 + p2;                                         \
    float t3 = c0 ? s7 + p7 : s3 + p3;                                         \
    float q0 = __shfl_xor(t0, 2), q1 = __shfl_xor(t1, 2);                      \
    float q2 = __shfl_xor(t2, 2), q3 = __shfl_xor(t3, 2);                      \
    float u0 = c1 ? t2 + q2 : t0 + q0;                                         \
    float u1 = c1 ? t3 + q3 : t1 + q1;                                         \
    float z0 = __shfl_xor(u0, 4), z1 = __shfl_xor(u1, 4);                      \
    float wvv = c2 ? u1 + z1 : u0 + z0;                                        \
    wvv += __shfl_xor(wvv, 8);                                                 \
    wvv += __shfl_xor(wvv, 16);                                                \
    wvv += __shfl_xor(wvv, 32);                                                \
    float lg0 = __shfl(wvv, 0), lg1 = __shfl(wvv, 4);                          \
    float lg2 = __shfl(wvv, 2), lg3 = __shfl(wvv, 6);                          \
    float lg4 = __shfl(wvv, 1), lg5 = __shfl(wvv, 5);                          \
    float lg6 = __shfl(wvv, 3), lg7 = __shfl(wvv, 7);                          \
    float mm = fmaxf(fmaxf(fmaxf(lg0, lg1), fmaxf(lg2, lg3)),                  \
                     fmaxf(fmaxf(lg4, lg5), fmaxf(lg6, lg7)));                 \
    float e0 = expf(lg0 - mm), e1 = expf(lg1 - mm);                            \
    float e2 = expf(lg2 - mm), e3 = expf(lg3 - mm);                            \
    float e4 = expf(lg4 - mm), e5 = expf(lg5 - mm);                            \
    float e6 = expf(lg6 - mm), e7 = expf(lg7 - mm);                            \
    float SS = e0 + e1 + e2 + e3 + e4 + e5 + e6 + e7;                          \
    float inv = 1.f / SS;                                                      \
    e0 *= inv; e1 *= inv; e2 *= inv; e3 *= inv;                                \
    e4 *= inv; e5 *= inv; e6 *= inv; e7 *= inv;                                \
    int b0 = 0; float v0 = e0;                                                 \
    if (e1 > v0) { b0 = 1; v0 = e1; }                                          \
    if (e2 > v0) { b0 = 2; v0 = e2; }                                          \
    if (e3 > v0) { b0 = 3; v0 = e3; }                                          \
    if (e4 > v0) { b0 = 4; v0 = e4; }                                          \
    if (e5 > v0) { b0 = 5; v0 = e5; }                                          \
    if (e6 > v0) { b0 = 6; v0 = e6; }                                          \
    if (e7 > v0) { b0 = 7; v0 = e7; }                                          \
    int b1 = -1; float v1 = -1.f;                                              \
    if (b0 != 0) { b1 = 0; v1 = e0; }                                          \
    if (b0 != 1 && e1 > v1) { b1 = 1; v1 = e1; }                               \
    if (b0 != 2 && e2 > v1) { b1 = 2; v1 = e2; }                               \
    if (b0 != 3 && e3 > v1) { b1 = 3; v1 = e3; }                               \
    if (b0 != 4 && e4 > v1) { b1 = 4; v1 = e4; }                               \
    if (b0 != 5 && e5 > v1) { b1 = 5; v1 = e5; }                               \
    if (b0 != 6 && e6 > v1) { b1 = 6; v1 = e6; }                               \
    if (b0 != 7 && e7 > v1) { b1 = 7; v1 = e7; }                               \
    float ssum = v0 + v1 + 1e-6f;                                              \
    if (lane == 0) {                                                           \
      sb0[slot] = b0; sb1[slot] = b1;                                          \
      sv0[slot] = v0 / ssum; sv1[slot] = v1 / ssum;                            \
      sp0[slot] = atomicAdd(&lcnt[b0], 1);                                     \
      sp1[slot] = atomicAdd(&lcnt[b1], 1);                                     \
    }                                                                          \
    bf16x8 hh;                                                                 \
    hh[0] = (bf16t)xv0.x; hh[1] = (bf16t)xv0.y;                                \
    hh[2] = (bf16t)xv0.z; hh[3] = (bf16t)xv0.w;                                \
    hh[4] = (bf16t)xv1.x; hh[5] = (bf16t)xv1.y;                                \
    hh[6] = (bf16t)xv1.z; hh[7] = (bf16t)xv1.w;                                \
    *(bf16x8*)(xb + (size_t)(nn)*HDIM + lane * 8) = hh;                        \
  }

__global__ __launch_bounds__(256, 2) void k_router(
    const float* __restrict__ x, const float* __restrict__ rw,
    int* __restrict__ cursor, bf16t* __restrict__ xb, int* __restrict__ btok,
    float* __restrict__ bw, int ntok) {
  __shared__ int lcnt[NEXP], gb[NEXP];
  __shared__ int sb0[16], sb1[16], sp0[16], sp1[16];
  __shared__ float sv0[16], sv1[16];
  int tid = threadIdx.x;
  if (tid < NEXP) lcnt[tid] = 0;
  __syncthreads();
  int lane = tid & 63;
  int c0 = lane & 1, c1 = (lane >> 1) & 1, c2 = (lane >> 2) & 1;
  int l2 = lane * 2;
  const float4* rwp = (const float4*)rw;
  float4 r0a = rwp[0 * 128 + l2], r0b = rwp[0 * 128 + l2 + 1];
  float4 r1a = rwp[1 * 128 + l2], r1b = rwp[1 * 128 + l2 + 1];
  float4 r2a = rwp[2 * 128 + l2], r2b = rwp[2 * 128 + l2 + 1];
  float4 r3a = rwp[3 * 128 + l2], r3b = rwp[3 * 128 + l2 + 1];
  float4 r4a = rwp[4 * 128 + l2], r4b = rwp[4 * 128 + l2 + 1];
  float4 r5a = rwp[5 * 128 + l2], r5b = rwp[5 * 128 + l2 + 1];
  float4 r6a = rwp[6 * 128 + l2], r6b = rwp[6 * 128 + l2 + 1];
  float4 r7a = rwp[7 * 128 + l2], r7b = rwp[7 * 128 + l2 + 1];
  int wv = tid >> 6;
  int nb = (blockIdx.x * 4 + wv) * 4;
  const float4* xp = (const float4*)x;
  int lastn = ntok - 1;
  int i0 = nb + 0 > lastn ? lastn : nb + 0;
  int i1 = nb + 1 > lastn ? lastn : nb + 1;
  int i2 = nb + 2 > lastn ? lastn : nb + 2;
  int i3 = nb + 3 > lastn ? lastn : nb + 3;
  float4 x0a = xp[(size_t)i0 * 128 + l2], x0b = xp[(size_t)i0 * 128 + l2 + 1];
  float4 x1a = xp[(size_t)i1 * 128 + l2], x1b = xp[(size_t)i1 * 128 + l2 + 1];
  float4 x2a = xp[(size_t)i2 * 128 + l2], x2b = xp[(size_t)i2 * 128 + l2 + 1];
  float4 x3a = xp[(size_t)i3 * 128 + l2], x3b = xp[(size_t)i3 * 128 + l2 + 1];
  ROUTE_TOKEN(nb + 0, x0a, x0b, wv * 4 + 0)
  ROUTE_TOKEN(nb + 1, x1a, x1b, wv * 4 + 1)
  ROUTE_TOKEN(nb + 2, x2a, x2b, wv * 4 + 2)
  ROUTE_TOKEN(nb + 3, x3a, x3b, wv * 4 + 3)
  __syncthreads();
  if (tid < NEXP) gb[tid] = lcnt[tid] ? atomicAdd(&cursor[tid], lcnt[tid]) : 0;
  __syncthreads();
  if (tid < 16) {
    int n = blockIdx.x * 16 + tid;
    if (n < ntok) {
      int b0 = sb0[tid], r0 = gb[b0] + sp0[tid];
      btok[b0 * ntok + r0] = n;              // slot 0
      bw[b0 * ntok + r0] = sv0[tid];
      int b1 = sb1[tid], r1 = gb[b1] + sp1[tid];
      btok[b1 * ntok + r1] = n | (1 << 30);  // slot 1
      bw[b1 * ntok + r1] = sv1[tid];
    }
  }
}

// -------- grouped GEMM: 128x128, BK=32, 4 waves, 3 bufs depth-2 -------------
// XCD-locality: expert = bid & 7 (== XCD under round-robin mapping), work item
// j = bid >> 3; rt = j>>2, ct = j&3 -> one expert's B panel (1MB) + xb slice
// (~2MB) stay hot in its XCD's private 4MB L2. Dead blocks exit on 1 load.
// Swizzle: LDS[row][c] holds global chunk c ^ ((row>>1)&3) (64B-pitch-correct
// involution); pre-swizzled global source, linear gload_lds dest, same XOR on
// read.
template <bool EO>
__global__ __launch_bounds__(256, 3) void k_gemm(
    const bf16t* __restrict__ xb, const bf16t* __restrict__ wT,
    const int* __restrict__ btok, const float* __restrict__ bw,
    const int* __restrict__ counts, bf16t* __restrict__ eout2,
    float* __restrict__ out, int ntok) {
  __shared__ bf16t Asm[3][BM * BK];  // 3 x 8KB
  __shared__ bf16t Bsm[3][BN * BK];  // 3 x 8KB
  int bid = blockIdx.x;
  int e = bid & 7;
  int j = bid >> 3;
  int rt = j >> 2, ct = j & 3;
  int cnt = counts[e];
  int m0 = rt * BM, n0 = ct * BN;
  if (m0 >= cnt) return;
  int tid = threadIdx.x;
  int lane = tid & 63;
  int wv = tid >> 6, wr = wv >> 1, wc = wv & 1;  // 2x2 wave grid

  // staging ids; source chunk pre-swizzled with (row>>1)&3
  int id0 = wv * 128 + lane;
  int id1 = wv * 128 + 64 + lane;
  int row0 = id0 >> 2, cc0 = (id0 & 3) ^ ((row0 >> 1) & 3);
  int row1 = id1 >> 2, cc1 = (id1 & 3) ^ ((row1 >> 1) & 3);
  const bf16t* bsrc0 = wT + (size_t)(e * HDIM + n0 + row0) * HDIM + cc0 * 8;
  const bf16t* bsrc1 = wT + (size_t)(e * HDIM + n0 + row1) * HDIM + cc1 * 8;
  int gr0 = m0 + row0; if (gr0 > cnt - 1) gr0 = cnt - 1;
  int gr1 = m0 + row1; if (gr1 > cnt - 1) gr1 = cnt - 1;
  int tok0 = btok[e * ntok + gr0] & 0xFFFFF;
  int tok1 = btok[e * ntok + gr1] & 0xFFFFF;
  const bf16t* asrc0 = xb + (size_t)tok0 * HDIM + cc0 * 8;
  const bf16t* asrc1 = xb + (size_t)tok1 * HDIM + cc1 * 8;
  int d0 = id0 * 8, d1 = id1 * 8;  // linear LDS dest (lane stride 16B)

  auto STAGE = [&](int b, int kt) {
    int k0 = kt * BK;
    gload_lds16(bsrc0 + k0, &Bsm[b][d0]);
    gload_lds16(bsrc1 + k0, &Bsm[b][d1]);
    gload_lds16(asrc0 + k0, &Asm[b][d0]);
    gload_lds16(asrc1 + k0, &Asm[b][d1]);
  };

  f32x4 acc[4][4];
#pragma unroll
  for (int a = 0; a < 4; ++a)
#pragma unroll
    for (int b = 0; b < 4; ++b) acc[a][b] = f32x4{0.f, 0.f, 0.f, 0.f};

  // read-side: global chunk g=lane>>4 at row r lives at lds chunk g^((r>>1)&3)
  int swk = ((lane >> 4) ^ ((lane >> 1) & 3)) * 8;
  int abase = (wr * 64 + (lane & 15)) * BK + swk;
  int bbase = (wc * 64 + (lane & 15)) * BK + swk;

  constexpr int NT = HDIM / BK;  // 16
  STAGE(0, 0);
  STAGE(1, 1);
#pragma unroll
  for (int kt = 0; kt < NT; ++kt) {
    int cur = kt % 3;
    if (kt + 2 < NT) STAGE((kt + 2) % 3, kt + 2);
    int nf = NT - 1 - kt;  // stages in flight beyond current
    if (nf >= 2)
      asm volatile("s_waitcnt vmcnt(8)" ::: "memory");
    else if (nf == 1)
      asm volatile("s_waitcnt vmcnt(4)" ::: "memory");
    else
      asm volatile("s_waitcnt vmcnt(0)" ::: "memory");
    __builtin_amdgcn_s_barrier();
    __builtin_amdgcn_sched_barrier(0);
    bf16x8 af[4], bfr[4];
#pragma unroll
    for (int mi = 0; mi < 4; ++mi)
      af[mi] = *(const bf16x8*)(&Asm[cur][abase + mi * 16 * BK]);
#pragma unroll
    for (int ni = 0; ni < 4; ++ni)
      bfr[ni] = *(const bf16x8*)(&Bsm[cur][bbase + ni * 16 * BK]);
#pragma unroll
    for (int mi = 0; mi < 4; ++mi)
#pragma unroll
      for (int ni = 0; ni < 4; ++ni)
        acc[mi][ni] =
            __builtin_amdgcn_mfma_f32_16x16x32_bf16(af[mi], bfr[ni], acc[mi][ni], 0, 0, 0);
    __builtin_amdgcn_s_barrier();  // frag reads done before buf reuse
    __builtin_amdgcn_sched_barrier(0);
  }

  // Epilogue: D[row][col]: col = lane&15, row = (lane>>4)*4 + j  [m89/m91]
  int col0 = n0 + wc * 64 + (lane & 15);
  int rb = wr * 64 + ((lane >> 4) << 2);
#pragma unroll
  for (int mi = 0; mi < 4; ++mi) {
#pragma unroll
    for (int jj = 0; jj < 4; ++jj) {
      int rrow = m0 + rb + mi * 16 + jj;
      if (rrow < cnt) {
        int entry = btok[e * ntok + rrow];
        int tok = entry & 0xFFFFF;
        int slot = (entry >> 30) & 1;
        float w = bw[e * ntok + rrow];
        if (EO) {
          bf16t* orow = eout2 + ((size_t)tok * 2 + slot) * HDIM + col0;
          orow[0] = (bf16t)(w * acc[mi][0][jj]);
          orow[16] = (bf16t)(w * acc[mi][1][jj]);
          orow[32] = (bf16t)(w * acc[mi][2][jj]);
          orow[48] = (bf16t)(w * acc[mi][3][jj]);
        } else {
          float* orow = out + (size_t)tok * HDIM + col0;
#pragma unroll
          for (int ni = 0; ni < 4; ++ni)
            atomicAdd(orow + ni * 16, w * acc[mi][ni][jj]);
        }
      }
    }
  }
}

// -------- combine: out[n] = eout2[2n] + eout2[2n+1]  (pure stream) ----------
__global__ void k_combine(const bf16t* __restrict__ eout2, float* __restrict__ out,
                          int ntok) {
  int lane = threadIdx.x & 63;
  int gw = (blockIdx.x * blockDim.x + threadIdx.x) >> 6;
  int nw = (gridDim.x * blockDim.x) >> 6;
  for (int n = gw; n < ntok; n += nw) {
    bf16x8 a = *(const bf16x8*)(eout2 + (size_t)(2 * n) * HDIM + lane * 8);
    bf16x8 b = *(const bf16x8*)(eout2 + (size_t)(2 * n + 1) * HDIM + lane * 8);
    float4 o0, o1;
    o0.x = (float)a[0] + (float)b[0];
    o0.y = (float)a[1] + (float)b[1];
    o0.z = (float)a[2] + (float)b[2];
    o0.w = (float)a[3] + (float)b[3];
    o1.x = (float)a[4] + (float)b[4];
    o1.y = (float)a[5] + (float)b[5];
    o1.z = (float)a[6] + (float)b[6];
    o1.w = (float)a[7] + (float)b[7];
    float4* dst = (float4*)(out + (size_t)n * HDIM + lane * 8);
    dst[0] = o0; dst[1] = o1;
  }
}

extern "C" void kernel_launch(void* const* d_in, const int* in_sizes, int n_in,
                              void* d_out, int out_size, void* d_ws, size_t ws_size,
                              hipStream_t stream) {
  const float* x = (const float*)d_in[0];
  const float* rw = (const float*)d_in[1];
  const float* W = (const float*)d_in[2];
  float* out = (float*)d_out;
  int ntok = in_sizes[0] / HDIM;  // 16384 for B=4,S=4096
  if (ntok <= 0) return;
  int maxJ = 4 * ((ntok + BM - 1) / BM);  // worst-case work items per expert

  // workspace layout
  char* ws = (char*)d_ws;
  size_t o = 0;
  bf16t* wT = (bf16t*)(ws + o); o += (size_t)NEXP * HDIM * HDIM * sizeof(bf16t);
  int* meta = (int*)(ws + o); o += 256;  // cursor/counts[8]
  int* cursor = meta;                    // doubles as counts after router
  int* btok = (int*)(ws + o); o += (size_t)NEXP * ntok * 4;   // [e][ntok]
  float* bw = (float*)(ws + o); o += (size_t)NEXP * ntok * 4;
  bf16t* xb = (bf16t*)(ws + o); o += (size_t)ntok * HDIM * sizeof(bf16t);
  size_t oBase = o;
  bf16t* eout2 = (bf16t*)(ws + o); o += (size_t)2 * ntok * HDIM * sizeof(bf16t);
  if (ws_size < oBase) return;           // ~23 MB minimum
  int useEO = (ws_size >= o) ? 1 : 0;    // +33.6 MB no-atomic path

  k_wt<<<dim3(512), dim3(256), 0, stream>>>(W, wT, cursor);
  k_router<<<dim3((ntok + 15) / 16), dim3(256), 0, stream>>>(x, rw, cursor, xb, btok, bw,
                                                             ntok);
  if (useEO) {
    k_gemm<true><<<dim3(NEXP * maxJ), dim3(256), 0, stream>>>(xb, wT, btok, bw, cursor,
                                                              eout2, out, ntok);
    k_combine<<<dim3(2048), dim3(256), 0, stream>>>(eout2, out, ntok);
  } else {
    k_zero<<<dim3(2048), dim3(256), 0, stream>>>((float4*)out, ntok * HDIM / 4);
    k_gemm<false><<<dim3(NEXP * maxJ), dim3(256), 0, stream>>>(xb, wT, btok, bw, cursor,
                                                               eout2, out, ntok);
  }
}